// Round 4
// baseline (146.450 us; speedup 1.0000x reference)
//
#include <hip/hip_runtime.h>
#include <math.h>

#define NN 200000
#define DD 64
#define BB 4096
#define KK 128
#define WW 20
#define HH 128

__device__ __forceinline__ float fast_rcp(float x) { return __builtin_amdgcn_rcpf(x); }
__device__ __forceinline__ float fast_rsq(float x) { return __builtin_amdgcn_rsqf(x); }

// ---------------- Kernel 1: neighbor attention aggregation only ----------------
// One block per target, 256 threads, ~6.5KB LDS.
// Pre-A : waves 0/1 gather neighbor scalars; wave 2 stages param table in LDS;
//         wave 3 computes target encoding (shuffle-reduced).
// Phase1: thread=(k=tid&127, half=tid>>7) computes 32 dims in-lane; params via
//         uniform-address LDS reads (broadcast).
// Phase2: lane=dim, wave=32 neighbors; recomputes feature, FMA-accumulates.
// feat2[b][128] = [tgt_feat(64) | neigh_agg(64)]
__global__ __launch_bounds__(256) void k1_encode(
    const float* __restrict__ adj_time, const float* __restrict__ gc,
    const float* __restrict__ cur_time, const float* __restrict__ neigh_mask,
    const float* __restrict__ t2v_w, const float* __restrict__ t2v_b,
    const float* __restrict__ node_w, const float* __restrict__ node_b,
    const float* __restrict__ att_w, const float* __restrict__ att_b,
    const int* __restrict__ targets, const int* __restrict__ neigh_idx,
    float* __restrict__ feat2)
{
    const int b    = blockIdx.x;
    const int tid  = threadIdx.x;
    const int lane = tid & 63;
    const int wid  = tid >> 6;
    const int k    = tid & 127;
    const int half = tid >> 7;

    __shared__ float4 p4[64];        // {t2v_w, t2v_b, node_w, node_b} per dim
    __shared__ float  aw2s[64];      // att_w[64+d]
    __shared__ float4 dtg[128];      // {dt, g, wk, -} per neighbor
    __shared__ float2 sp[2][128];    // {s2, sd} partials per half
    __shared__ float  aggp[4][64];
    __shared__ float  stL;

    const float t = cur_time[0];

    // ---- pre-A ----
    float ts_k = 0.f, m_k = 0.f;
    if (tid < 128) {                 // waves 0,1: neighbor gathers (once)
        int   idx = neigh_idx[b * KK + k];
        m_k       = neigh_mask[b * KK + k];
        float at  = adj_time[idx];
        float g   = gc[idx];
        dtg[k]    = make_float4(fabsf(t - at), g, 0.f, 0.f);
        ts_k      = fast_rcp(2.0f * __logf(2.71828182845904523536f + (t - at)));
    } else if (wid == 2) {           // wave 2: stage param table
        p4[lane]   = make_float4(t2v_w[lane], t2v_b[lane], node_w[lane], node_b[lane]);
        aw2s[lane] = att_w[64 + lane];
    } else {                         // wave 3: target encoding
        int   tg  = targets[b];
        float dtT = fabsf(t - adj_time[tg]);
        float gT  = gc[tg];
        float ph  = fmaf(t2v_w[lane], dtT, t2v_b[lane]);
        float tv  = (lane == 0) ? ph : __cosf(ph);
        float f   = fmaxf(tv + fmaf(gT, node_w[lane], node_b[lane]), 0.f);
        float ss  = f * f;
#pragma unroll
        for (int off = 32; off; off >>= 1) ss += __shfl_xor(ss, off, 64);
        float invn = fast_rsq(fmaxf(ss, 1e-24f));
        float tfn  = f * invn;
        float sdt  = tfn * att_w[lane];
#pragma unroll
        for (int off = 32; off; off >>= 1) sdt += __shfl_xor(sdt, off, 64);
        if (lane == 0) stL = sdt;
        feat2[b * 128 + lane] = tfn;
    }
    __syncthreads();   // A: dtg, p4, aw2s, stL ready

    // ---- phase 1: per-(k,half) 32 dims in-lane; params via LDS broadcast ----
    {
        float4 dg = dtg[k];
        float  dt = dg.x, g = dg.y;
        float  s2 = 0.f, sd = 0.f;
        const int d0 = half * 32;
#pragma unroll
        for (int dd = 0; dd < 32; ++dd) {
            int    d  = d0 + dd;                // wave-uniform LDS addr -> broadcast
            float4 p  = p4[d];
            float  a2 = aw2s[d];
            float  ph = fmaf(p.x, dt, p.y);
            float  cv = __cosf(ph);
            float  tv = (d == 0) ? ph : cv;
            float  f  = fmaxf(tv + fmaf(g, p.z, p.w), 0.f);
            s2 = fmaf(f, f, s2);
            sd = fmaf(f, a2, sd);
        }
        sp[half][k] = make_float2(s2, sd);
    }
    __syncthreads();   // B: sp ready

    if (!half) {
        float2 a0 = sp[0][k], a1 = sp[1][k];
        float  s2 = a0.x + a1.x;
        float  sd = a0.y + a1.y;
        float  invn = fast_rsq(fmaxf(s2, 1e-24f));
        float  sc = ts_k + stL + sd * invn + att_b[0];
        sc = (sc > 0.f) ? sc : 0.01f * sc;     // leaky_relu(0.01)
        dtg[k].z = sc * m_k * invn;
    }
    __syncthreads();   // C: wk ready

    // ---- phase 2: lane=dim, wave wid recomputes 32 neighbors, FMA-accumulate ----
    {
        float4 pl = p4[lane];
        float acc = 0.f;
        const int k0 = wid * 32;
#pragma unroll 8
        for (int j = 0; j < 32; ++j) {
            float4 dg = dtg[k0 + j];            // uniform addr -> broadcast
            float  ph = fmaf(pl.x, dg.x, pl.y);
            float  cv = __cosf(ph);
            float  tv = (lane == 0) ? ph : cv;
            float  f  = fmaxf(tv + fmaf(dg.y, pl.z, pl.w), 0.f);
            acc = fmaf(dg.z, f, acc);
        }
        aggp[wid][lane] = acc;
    }
    __syncthreads();   // D

    if (tid < 64) {
        feat2[b * 128 + 64 + tid] =
            aggp[0][tid] + aggp[1][tid] + aggp[2][tid] + aggp[3][tid];
    }
}

// ---------------- Kernel 2: history aggregation + out = relu(feat4 @ W^T) ----------------
// 512 blocks x 256 thr; block handles 8 targets. Builds feat4 tile in LDS:
// cols 0-127 = hist_agg (streamed here, overlaps GEMM staging), 128-255 = feat2.
__global__ __launch_bounds__(256) void k2_gemm(
    const float* __restrict__ feat2, const float* __restrict__ weight,
    const float* __restrict__ hist_feat, const float* __restrict__ hist_time,
    const float* __restrict__ cur_time, float* __restrict__ out)
{
    const int b0  = blockIdx.x * 8;
    const int tid = threadIdx.x;

    __shared__ float tile[8 * 256];      // feat4 rows for 8 targets
    __shared__ float wl[128 * 33];       // W chunk [128 h][32 j], pad 33
    __shared__ float hwsL[8][WW];        // per-target history decay weights

    const float t = cur_time[0];

    // ---- stage hws (160 values) + feat2 halves of tile ----
    if (tid < 8 * WW) {
        int r = tid / WW, w = tid % WW;
        hwsL[r][w] = fast_rcp(2.0f * (1.0f + (t - hist_time[(b0 + r) * WW + w])));
    }
    {
        // 8 targets x 128 floats = 1024 floats = 256 float4, one per thread
        int fi = tid * 4;
        int r  = fi >> 7;
        int dc = fi & 127;
        float4 v = *(const float4*)(feat2 + (size_t)(b0 + r) * 128 + dc);
        *(float4*)(tile + r * 256 + 128 + dc) = v;
    }
    __syncthreads();   // hwsL ready

    // ---- history aggregation into tile cols 0-127 ----
    {
        int d  = tid & 127;
        int rg = tid >> 7;          // 0: targets 0-3, 1: targets 4-7
#pragma unroll
        for (int rr = 0; rr < 4; ++rr) {
            int r = rg * 4 + rr;
            const float* hf = hist_feat + (size_t)(b0 + r) * WW * 128 + d;
            float s = 0.f;
#pragma unroll
            for (int w = 0; w < WW; ++w) {
                s = fmaf(hwsL[r][w], __builtin_nontemporal_load(hf + w * 128), s);
            }
            tile[r * 256 + d] = s;
        }
    }

    const int h = tid & 127;
    const int g = tid >> 7;
    const float* tb = tile + (g * 4) * 256;

    float acc0 = 0.f, acc1 = 0.f, acc2 = 0.f, acc3 = 0.f;

    for (int c = 0; c < 8; ++c) {
        __syncthreads();   // protects wl overwrite; at c=0 covers tile writes
#pragma unroll
        for (int i = 0; i < 16; ++i) {
            int l  = i * 256 + tid;
            int hh = l >> 5;
            int jj = l & 31;
            wl[hh * 33 + jj] = weight[hh * 256 + c * 32 + jj];
        }
        __syncthreads();

#pragma unroll
        for (int jj = 0; jj < 32; jj += 4) {
            float w0 = wl[h * 33 + jj + 0];
            float w1 = wl[h * 33 + jj + 1];
            float w2 = wl[h * 33 + jj + 2];
            float w3 = wl[h * 33 + jj + 3];
            float4 f0 = *(const float4*)(tb + 0 * 256 + c * 32 + jj);
            float4 f1 = *(const float4*)(tb + 1 * 256 + c * 32 + jj);
            float4 f2 = *(const float4*)(tb + 2 * 256 + c * 32 + jj);
            float4 f3 = *(const float4*)(tb + 3 * 256 + c * 32 + jj);
            acc0 += w0 * f0.x + w1 * f0.y + w2 * f0.z + w3 * f0.w;
            acc1 += w0 * f1.x + w1 * f1.y + w2 * f1.z + w3 * f1.w;
            acc2 += w0 * f2.x + w1 * f2.y + w2 * f2.z + w3 * f2.w;
            acc3 += w0 * f3.x + w1 * f3.y + w2 * f3.z + w3 * f3.w;
        }
    }

    out[(size_t)(b0 + g * 4 + 0) * 128 + h] = fmaxf(acc0, 0.f);
    out[(size_t)(b0 + g * 4 + 1) * 128 + h] = fmaxf(acc1, 0.f);
    out[(size_t)(b0 + g * 4 + 2) * 128 + h] = fmaxf(acc2, 0.f);
    out[(size_t)(b0 + g * 4 + 3) * 128 + h] = fmaxf(acc3, 0.f);
}

extern "C" void kernel_launch(void* const* d_in, const int* in_sizes, int n_in,
                              void* d_out, int out_size, void* d_ws, size_t ws_size,
                              hipStream_t stream) {
    const float* adj_time  = (const float*)d_in[0];
    const float* gc        = (const float*)d_in[1];
    const float* cur_time  = (const float*)d_in[2];
    const float* neigh_mask= (const float*)d_in[3];
    const float* hist_feat = (const float*)d_in[4];
    const float* hist_time = (const float*)d_in[5];
    const float* t2v_w     = (const float*)d_in[6];
    const float* t2v_b     = (const float*)d_in[7];
    const float* node_w    = (const float*)d_in[8];
    const float* node_b    = (const float*)d_in[9];
    const float* att_w     = (const float*)d_in[10];
    const float* att_b     = (const float*)d_in[11];
    const float* weight    = (const float*)d_in[12];
    const int*   targets   = (const int*)d_in[13];
    const int*   neigh_idx = (const int*)d_in[14];

    float* out   = (float*)d_out;
    float* feat2 = (float*)d_ws;   // B*128 floats = 2 MB

    k1_encode<<<BB, 256, 0, stream>>>(adj_time, gc, cur_time, neigh_mask,
                                      t2v_w, t2v_b, node_w, node_b,
                                      att_w, att_b, targets, neigh_idx, feat2);

    k2_gemm<<<BB / 8, 256, 0, stream>>>(feat2, weight, hist_feat, hist_time,
                                        cur_time, out);
}

// Round 5
// 144.314 us; speedup vs baseline: 1.0148x; 1.0148x over previous
//
#include <hip/hip_runtime.h>
#include <math.h>

#define NN 200000
#define DD 64
#define BB 4096
#define KK 128
#define WW 20
#define HH 128

__device__ __forceinline__ float fast_rcp(float x) { return __builtin_amdgcn_rcpf(x); }
__device__ __forceinline__ float fast_rsq(float x) { return __builtin_amdgcn_rsqf(x); }

// ---------------- Kernel 1 ----------------
// One block per target, 256 threads, ~6KB LDS (8 blocks/CU resident).
// Pre-A : waves 0/1 gather neighbor scalars (once), wave 2 history weights,
//         wave 3 target encoding (shuffle-reduced).
// Phase1: thread=(k=tid&127, half=tid>>7) computes 32 dims in-lane; params via
//         plain VMEM loads (same-address broadcast, L1-hit; vmcnt pipe --
//         deliberately NOT readfirstlane/s_load: SMEM would share the in-order
//         lgkmcnt with the LDS reads and serialize the loop).
// Phase2: lane=dim, wave=32 neighbors; RECOMPUTES feature (cos is cheap),
//         accumulates wk[k]*f[k][lane] with plain FMAs.
// feat4[b][256] = [hist_agg(128) | tgt_feat(64) | neigh_agg(64)]
__global__ __launch_bounds__(256) void k1_encode(
    const float* __restrict__ adj_time, const float* __restrict__ gc,
    const float* __restrict__ cur_time, const float* __restrict__ neigh_mask,
    const float* __restrict__ hist_feat, const float* __restrict__ hist_time,
    const float* __restrict__ t2v_w, const float* __restrict__ t2v_b,
    const float* __restrict__ node_w, const float* __restrict__ node_b,
    const float* __restrict__ att_w, const float* __restrict__ att_b,
    const int* __restrict__ targets, const int* __restrict__ neigh_idx,
    float* __restrict__ feat4)
{
    const int b    = blockIdx.x;
    const int tid  = threadIdx.x;
    const int lane = tid & 63;
    const int wid  = tid >> 6;
    const int k    = tid & 127;
    const int half = tid >> 7;

    __shared__ float  hws[WW];
    __shared__ float  hpart[128];
    __shared__ float4 dtg[128];      // {dt, g, wk, -} per neighbor
    __shared__ float2 sp[2][128];    // {s2, sd} partials per half
    __shared__ float  aggp[4][64];
    __shared__ float  stL;

    const float t = cur_time[0];

    // ---- pre-A: gathers (waves 0,1), hist weights (wave 2), target enc (wave 3) ----
    float ts_k = 0.f, m_k = 0.f;
    if (tid < 128) {
        int   idx = neigh_idx[b * KK + k];
        m_k       = neigh_mask[b * KK + k];
        float at  = adj_time[idx];
        float g   = gc[idx];
        float dt  = fabsf(t - at);
        dtg[k]    = make_float4(dt, g, 0.f, 0.f);
        ts_k      = fast_rcp(2.0f * __logf(2.71828182845904523536f + (t - at)));
    } else if (wid == 2) {
        if (lane < WW)
            hws[lane] = fast_rcp(2.0f * (1.0f + (t - hist_time[b * WW + lane])));
    } else { // wave 3: target encoding
        int   tg  = targets[b];
        float dtT = fabsf(t - adj_time[tg]);
        float gT  = gc[tg];
        float pw  = t2v_w[lane], pb = t2v_b[lane];
        float nw  = node_w[lane], nb2 = node_b[lane];
        float ph  = fmaf(pw, dtT, pb);
        float tv  = (lane == 0) ? ph : __cosf(ph);
        float f   = fmaxf(tv + fmaf(gT, nw, nb2), 0.f);
        float ss  = f * f;
#pragma unroll
        for (int off = 32; off; off >>= 1) ss += __shfl_xor(ss, off, 64);
        float invn = fast_rsq(fmaxf(ss, 1e-24f));
        float tfn  = f * invn;
        float sdt  = tfn * att_w[lane];
#pragma unroll
        for (int off = 32; off; off >>= 1) sdt += __shfl_xor(sdt, off, 64);
        if (lane == 0) stL = sdt;
        feat4[b * 256 + 128 + lane] = tfn;
    }
    __syncthreads();   // A: dtg, hws, stL ready

    // ---- history loads into registers (HBM latency overlaps phase-1 VALU) ----
    float hv[10];
    {
        const float* hf = hist_feat + (size_t)b * WW * 128 + (tid & 127);
#pragma unroll
        for (int w = 0; w < 10; ++w) hv[w] = hf[(half * 10 + w) * 128];
    }

    // ---- phase 1: per-(k,half) 32 dims in-lane; params via VMEM broadcast ----
    {
        const int d0 = half * 32;
        float4 dg = dtg[k];
        float  dt = dg.x, g = dg.y;
        float  s2 = 0.f, sd = 0.f;
#pragma unroll
        for (int dd = 0; dd < 32; ++dd) {
            int   d   = d0 + dd;               // NOT forced uniform: vector VMEM
            float pw  = t2v_w[d], pb = t2v_b[d];
            float nw  = node_w[d], nb2 = node_b[d];
            float a2  = att_w[64 + d];
            float ph  = fmaf(pw, dt, pb);
            float cv  = __cosf(ph);
            float tv  = (d == 0) ? ph : cv;
            float f   = fmaxf(tv + fmaf(g, nw, nb2), 0.f);
            s2 = fmaf(f, f, s2);
            sd = fmaf(f, a2, sd);
        }
        sp[half][k] = make_float2(s2, sd);
    }

    // ---- history partial combine (hws already read; hv in regs) ----
    float hsum = 0.f;
#pragma unroll
    for (int w = 0; w < 10; ++w) hsum = fmaf(hws[half * 10 + w], hv[w], hsum);
    if (half) hpart[tid & 127] = hsum;

    __syncthreads();   // B: sp + hpart consumed next

    if (!half) {
        // history final
        feat4[b * 256 + (tid & 127)] = hsum + hpart[tid & 127];
        // neighbor weight wk[k]
        float2 a0 = sp[0][k], a1 = sp[1][k];
        float  s2 = a0.x + a1.x;
        float  sd = a0.y + a1.y;
        float  invn = fast_rsq(fmaxf(s2, 1e-24f));
        float  sc = ts_k + stL + sd * invn + att_b[0];
        sc = (sc > 0.f) ? sc : 0.01f * sc;     // leaky_relu(0.01)
        dtg[k].z = sc * m_k * invn;
    }
    __syncthreads();   // C: wk ready

    // ---- phase 2: lane=dim, wave wid recomputes 32 neighbors, FMA-accumulate ----
    {
        float pw  = t2v_w[lane], pb = t2v_b[lane];
        float nw  = node_w[lane], nb2 = node_b[lane];
        float acc = 0.f;
        const int k0 = wid * 32;
#pragma unroll 8
        for (int j = 0; j < 32; ++j) {
            float4 dg = dtg[k0 + j];            // uniform addr -> broadcast
            float  ph = fmaf(pw, dg.x, pb);
            float  cv = __cosf(ph);
            float  tv = (lane == 0) ? ph : cv;
            float  f  = fmaxf(tv + fmaf(dg.y, nw, nb2), 0.f);
            acc = fmaf(dg.z, f, acc);
        }
        aggp[wid][lane] = acc;
    }
    __syncthreads();   // D

    if (tid < 64) {
        feat4[b * 256 + 192 + tid] =
            aggp[0][tid] + aggp[1][tid] + aggp[2][tid] + aggp[3][tid];
    }
}

// ---------------- Kernel 2: out = relu(feat4 @ weight^T) ----------------
// (identical to the R3 best-known version)
__global__ __launch_bounds__(256) void k2_gemm(
    const float* __restrict__ feat4, const float* __restrict__ weight,
    float* __restrict__ out)
{
    const int b0  = blockIdx.x * 8;
    const int tid = threadIdx.x;

    __shared__ float tile[8 * 256];      // feat rows
    __shared__ float wl[128 * 33];       // W chunk [128 h][32 j], pad 33

    {
        const float4* src = (const float4*)(feat4 + (size_t)b0 * 256);
        float4* dst = (float4*)tile;
        dst[tid]       = src[tid];
        dst[tid + 256] = src[tid + 256];
    }

    const int h = tid & 127;
    const int g = tid >> 7;
    const float* tb = tile + (g * 4) * 256;

    float acc0 = 0.f, acc1 = 0.f, acc2 = 0.f, acc3 = 0.f;

    for (int c = 0; c < 8; ++c) {
        __syncthreads();   // protects wl overwrite (covers tile load on c=0)
#pragma unroll
        for (int i = 0; i < 16; ++i) {
            int l  = i * 256 + tid;
            int hh = l >> 5;
            int jj = l & 31;
            wl[hh * 33 + jj] = weight[hh * 256 + c * 32 + jj];
        }
        __syncthreads();

#pragma unroll
        for (int jj = 0; jj < 32; jj += 4) {
            float w0 = wl[h * 33 + jj + 0];
            float w1 = wl[h * 33 + jj + 1];
            float w2 = wl[h * 33 + jj + 2];
            float w3 = wl[h * 33 + jj + 3];
            float4 f0 = *(const float4*)(tb + 0 * 256 + c * 32 + jj);
            float4 f1 = *(const float4*)(tb + 1 * 256 + c * 32 + jj);
            float4 f2 = *(const float4*)(tb + 2 * 256 + c * 32 + jj);
            float4 f3 = *(const float4*)(tb + 3 * 256 + c * 32 + jj);
            acc0 += w0 * f0.x + w1 * f0.y + w2 * f0.z + w3 * f0.w;
            acc1 += w0 * f1.x + w1 * f1.y + w2 * f1.z + w3 * f1.w;
            acc2 += w0 * f2.x + w1 * f2.y + w2 * f2.z + w3 * f2.w;
            acc3 += w0 * f3.x + w1 * f3.y + w2 * f3.z + w3 * f3.w;
        }
    }

    out[(size_t)(b0 + g * 4 + 0) * 128 + h] = fmaxf(acc0, 0.f);
    out[(size_t)(b0 + g * 4 + 1) * 128 + h] = fmaxf(acc1, 0.f);
    out[(size_t)(b0 + g * 4 + 2) * 128 + h] = fmaxf(acc2, 0.f);
    out[(size_t)(b0 + g * 4 + 3) * 128 + h] = fmaxf(acc3, 0.f);
}

extern "C" void kernel_launch(void* const* d_in, const int* in_sizes, int n_in,
                              void* d_out, int out_size, void* d_ws, size_t ws_size,
                              hipStream_t stream) {
    const float* adj_time  = (const float*)d_in[0];
    const float* gc        = (const float*)d_in[1];
    const float* cur_time  = (const float*)d_in[2];
    const float* neigh_mask= (const float*)d_in[3];
    const float* hist_feat = (const float*)d_in[4];
    const float* hist_time = (const float*)d_in[5];
    const float* t2v_w     = (const float*)d_in[6];
    const float* t2v_b     = (const float*)d_in[7];
    const float* node_w    = (const float*)d_in[8];
    const float* node_b    = (const float*)d_in[9];
    const float* att_w     = (const float*)d_in[10];
    const float* att_b     = (const float*)d_in[11];
    const float* weight    = (const float*)d_in[12];
    const int*   targets   = (const int*)d_in[13];
    const int*   neigh_idx = (const int*)d_in[14];

    float* out   = (float*)d_out;
    float* feat4 = (float*)d_ws;   // B*256 floats = 4 MB

    k1_encode<<<BB, 256, 0, stream>>>(adj_time, gc, cur_time, neigh_mask,
                                      hist_feat, hist_time, t2v_w, t2v_b,
                                      node_w, node_b, att_w, att_b,
                                      targets, neigh_idx, feat4);

    k2_gemm<<<BB / 8, 256, 0, stream>>>(feat4, weight, out);
}

// Round 6
// 135.646 us; speedup vs baseline: 1.0796x; 1.0639x over previous
//
#include <hip/hip_runtime.h>
#include <math.h>

#define NN 200000
#define DD 64
#define BB 4096
#define KK 128
#define WW 20
#define HH 128
#define TPB 512
#define RPB 8    // targets per block

__device__ __forceinline__ float fast_rcp(float x) { return __builtin_amdgcn_rcpf(x); }
__device__ __forceinline__ float fast_rsq(float x) { return __builtin_amdgcn_rsqf(x); }

// Fully-fused pipeline: 512 blocks x 512 threads, 8 targets/block (2 blocks/CU,
// single occupancy round). Per block:
//   pre-A : gathers (2 slots/thread), hws, per-wave target encodings (wave w =
//           target w; tgt_feat written straight into the LDS feat4 tile).
//   phase1: thread computes full 64-dim feature norm+att-dot for its 2 slots
//           in-lane (params via uniform s_loads -- R3's winning scheme) and
//           writes wk[slot] directly (no sp exchange, no aggp).
//   hist  : 2 (r,d) columns/thread, 20-tap decay FMA into tile cols 0-127.
//   phase3: wave w re-computes features for target w's 128 neighbors
//           (lane=dim), FMA-accumulates into tile cols 192-255.
//   GEMM  : relu(tile @ W^T) with W staged chunk-wise in LDS (pad-33).
// feat4 never touches HBM; no second launch.
__global__ __launch_bounds__(512, 4) void fused(
    const float* __restrict__ adj_time, const float* __restrict__ gc,
    const float* __restrict__ cur_time, const float* __restrict__ neigh_mask,
    const float* __restrict__ hist_feat, const float* __restrict__ hist_time,
    const float* __restrict__ t2v_w, const float* __restrict__ t2v_b,
    const float* __restrict__ node_w, const float* __restrict__ node_b,
    const float* __restrict__ att_w, const float* __restrict__ att_b,
    const float* __restrict__ weight,
    const int* __restrict__ targets, const int* __restrict__ neigh_idx,
    float* __restrict__ out)
{
    const int b0   = blockIdx.x * RPB;
    const int tid  = threadIdx.x;
    const int lane = tid & 63;
    const int wv   = tid >> 6;          // wave id 0..7 == target row

    __shared__ float2 dtg[RPB * KK];    // {dt, g} per (target, neighbor)   8 KB
    __shared__ float  wk[RPB * KK];     // per-neighbor weight              4 KB
    __shared__ float  hws[RPB][WW];     // history decay weights          640 B
    __shared__ float  stL[RPB];         // target att-dot per row
    __shared__ float  tile[RPB * 256];  // feat4 rows                       8 KB
    __shared__ float  wl[128 * 33];     // W chunk [128 h][32 j], pad 33   ~17 KB

    const float t = cur_time[0];

    // ---- pre-A: gathers (2 slots/thread) ----
    float ts_r[2], m_r[2];
#pragma unroll
    for (int i = 0; i < 2; ++i) {
        int   slot = tid + i * TPB;                 // slot = r*128 + k
        int   idx  = neigh_idx[b0 * KK + slot];
        m_r[i]     = neigh_mask[b0 * KK + slot];
        float at   = adj_time[idx];
        float g    = gc[idx];
        dtg[slot]  = make_float2(fabsf(t - at), g);
        ts_r[i]    = fast_rcp(2.0f * __logf(2.71828182845904523536f + (t - at)));
    }
    // ---- pre-A: history decay weights ----
    if (tid < RPB * WW) {
        int r = tid / WW, w = tid - r * WW;
        hws[r][w] = fast_rcp(2.0f * (1.0f + (t - hist_time[(b0 + r) * WW + w])));
    }
    // ---- pre-A: target encoding, wave wv -> target wv ----
    {
        int   tg  = targets[b0 + wv];
        float dtT = fabsf(t - adj_time[tg]);
        float gT  = gc[tg];
        float ph  = fmaf(t2v_w[lane], dtT, t2v_b[lane]);
        float tv_ = (lane == 0) ? ph : __cosf(ph);
        float f   = fmaxf(tv_ + fmaf(gT, node_w[lane], node_b[lane]), 0.f);
        float ss  = f * f;
#pragma unroll
        for (int off = 32; off; off >>= 1) ss += __shfl_xor(ss, off, 64);
        float invn = fast_rsq(fmaxf(ss, 1e-24f));
        float tfn  = f * invn;
        float sdt  = tfn * att_w[lane];
#pragma unroll
        for (int off = 32; off; off >>= 1) sdt += __shfl_xor(sdt, off, 64);
        if (lane == 0) stL[wv] = sdt;
        tile[wv * 256 + 128 + lane] = tfn;
    }
    __syncthreads();   // A: dtg, hws, stL ready

    // ---- phase 1: full 64-dim in-lane per slot; params via literal-offset s_loads ----
    const float ab = att_b[0];
#pragma unroll
    for (int i = 0; i < 2; ++i) {
        int    slot = tid + i * TPB;
        int    r    = slot >> 7;
        float2 dg   = dtg[slot];
        float  s2 = 0.f, sd = 0.f;
#pragma unroll 8
        for (int d = 0; d < 64; ++d) {
            float ph  = fmaf(t2v_w[d], dg.x, t2v_b[d]);
            float cv  = __cosf(ph);
            float tv_ = (d == 0) ? ph : cv;
            float f   = fmaxf(tv_ + fmaf(dg.y, node_w[d], node_b[d]), 0.f);
            s2 = fmaf(f, f, s2);
            sd = fmaf(f, att_w[64 + d], sd);
        }
        float invn = fast_rsq(fmaxf(s2, 1e-24f));
        float sc   = ts_r[i] + stL[r] + sd * invn + ab;
        sc = (sc > 0.f) ? sc : 0.01f * sc;          // leaky_relu(0.01)
        wk[slot] = sc * m_r[i] * invn;
    }

    // ---- history aggregation into tile cols 0-127 (2 columns/thread) ----
#pragma unroll
    for (int i = 0; i < 2; ++i) {
        int col = tid + i * TPB;
        int r = col >> 7, d = col & 127;
        const float* hf = hist_feat + (size_t)(b0 + r) * WW * 128 + d;
        float s = 0.f;
#pragma unroll
        for (int w = 0; w < WW; ++w) s = fmaf(hws[r][w], hf[w * 128], s);
        tile[r * 256 + d] = s;
    }
    __syncthreads();   // C: wk ready

    // ---- phase 3: wave wv owns target wv; lane = dim; recompute + FMA ----
    {
        float pw = t2v_w[lane], pb = t2v_b[lane];
        float nw = node_w[lane], nb2 = node_b[lane];
        float acc = 0.f;
        const int base = wv * KK;
#pragma unroll 8
        for (int k = 0; k < KK; ++k) {
            float2 dg = dtg[base + k];              // uniform addr -> broadcast
            float  w_ = wk[base + k];
            float  ph = fmaf(pw, dg.x, pb);
            float  cv = __cosf(ph);
            float  tv_ = (lane == 0) ? ph : cv;
            float  f  = fmaxf(tv_ + fmaf(dg.y, nw, nb2), 0.f);
            acc = fmaf(w_, f, acc);
        }
        tile[wv * 256 + 192 + lane] = acc;
    }

    // ---- GEMM: out = relu(tile @ W^T); thread = (h, g), 2 targets/thread ----
    const int h = tid & 127;
    const int g = tid >> 7;                         // 0..3 -> rows {2g, 2g+1}
    const float* tb = tile + (g * 2) * 256;
    float acc0 = 0.f, acc1 = 0.f;

    for (int c = 0; c < 8; ++c) {
        __syncthreads();   // c=0: covers phase-3/hist tile writes; else: wl reuse
#pragma unroll
        for (int i = 0; i < 8; ++i) {
            int l  = i * TPB + tid;
            int hh = l >> 5, jj = l & 31;
            wl[hh * 33 + jj] = weight[hh * 256 + c * 32 + jj];
        }
        __syncthreads();

#pragma unroll
        for (int jj = 0; jj < 32; jj += 4) {
            float w0 = wl[h * 33 + jj + 0];
            float w1 = wl[h * 33 + jj + 1];
            float w2 = wl[h * 33 + jj + 2];
            float w3 = wl[h * 33 + jj + 3];
            float4 f0 = *(const float4*)(tb + 0 * 256 + c * 32 + jj);
            float4 f1 = *(const float4*)(tb + 1 * 256 + c * 32 + jj);
            acc0 += w0 * f0.x + w1 * f0.y + w2 * f0.z + w3 * f0.w;
            acc1 += w0 * f1.x + w1 * f1.y + w2 * f1.z + w3 * f1.w;
        }
    }

    out[(size_t)(b0 + g * 2 + 0) * 128 + h] = fmaxf(acc0, 0.f);
    out[(size_t)(b0 + g * 2 + 1) * 128 + h] = fmaxf(acc1, 0.f);
}

extern "C" void kernel_launch(void* const* d_in, const int* in_sizes, int n_in,
                              void* d_out, int out_size, void* d_ws, size_t ws_size,
                              hipStream_t stream) {
    const float* adj_time  = (const float*)d_in[0];
    const float* gc        = (const float*)d_in[1];
    const float* cur_time  = (const float*)d_in[2];
    const float* neigh_mask= (const float*)d_in[3];
    const float* hist_feat = (const float*)d_in[4];
    const float* hist_time = (const float*)d_in[5];
    const float* t2v_w     = (const float*)d_in[6];
    const float* t2v_b     = (const float*)d_in[7];
    const float* node_w    = (const float*)d_in[8];
    const float* node_b    = (const float*)d_in[9];
    const float* att_w     = (const float*)d_in[10];
    const float* att_b     = (const float*)d_in[11];
    const float* weight    = (const float*)d_in[12];
    const int*   targets   = (const int*)d_in[13];
    const int*   neigh_idx = (const int*)d_in[14];

    float* out = (float*)d_out;

    fused<<<BB / RPB, TPB, 0, stream>>>(adj_time, gc, cur_time, neigh_mask,
                                        hist_feat, hist_time, t2v_w, t2v_b,
                                        node_w, node_b, att_w, att_b, weight,
                                        targets, neigh_idx, out);
}